// Round 1
// baseline (1657.953 us; speedup 1.0000x reference)
//
#include <hip/hip_runtime.h>
#include <hip/hip_bf16.h>
#include <math.h>

#define N_NODES 100000
#define N_EDGES 1600000
#define IN_CH 256
#define HC 128
#define NEG_SLOPE 0.2f

// ---------------------------------------------------------------------------
// Kernel 1: feat = x @ W^T + b.  x:(N,256) W:(128,256) feat:(N,128), fp32.
// BM=64 x BN=128 tile, BK=32, 256 threads, thread computes 4 rows x 8 cols.
// ---------------------------------------------------------------------------
#define BM 64
#define BN 128
#define BK 32

__global__ __launch_bounds__(256, 2)
void gemm_feat(const float* __restrict__ x, const float* __restrict__ W,
               const float* __restrict__ b, float* __restrict__ feat) {
    __shared__ float xs[BM][BK + 1];     // +1 pad: break bank aliasing on column reads
    __shared__ float wsh[BK][BN + 4];    // +4 pad keeps 16B alignment for float4 reads

    const int tid  = threadIdx.x;
    const int m_blk = blockIdx.x * BM;
    const int nthr = tid & 15;           // 16 col-groups of 8
    const int mthr = tid >> 4;           // 16 row-groups of 4
    const int n0 = nthr * 8;
    const int m0 = mthr * 4;

    float acc[4][8];
    #pragma unroll
    for (int r = 0; r < 4; ++r)
        #pragma unroll
        for (int c = 0; c < 8; ++c) acc[r][c] = 0.f;

    for (int k0 = 0; k0 < IN_CH; k0 += BK) {
        // stage x tile (64 rows x 32 k): 2 float4 per thread
        {
            const int f = tid & 7;
            const int row = tid >> 3;    // 0..31
            #pragma unroll
            for (int i = 0; i < 2; ++i) {
                int r = row + i * 32;
                int gm = m_blk + r;
                float4 v = make_float4(0.f, 0.f, 0.f, 0.f);
                if (gm < N_NODES)
                    v = *(const float4*)&x[(size_t)gm * IN_CH + k0 + f * 4];
                xs[r][f * 4 + 0] = v.x; xs[r][f * 4 + 1] = v.y;
                xs[r][f * 4 + 2] = v.z; xs[r][f * 4 + 3] = v.w;
            }
        }
        // stage W tile transposed into wsh[k][n]: 4 float4 per thread
        {
            const int f = tid & 7;       // k-float4 within chunk
            const int nb = tid >> 3;     // 0..31
            #pragma unroll
            for (int i = 0; i < 4; ++i) {
                int n = nb + i * 32;
                float4 v = *(const float4*)&W[(size_t)n * IN_CH + k0 + f * 4];
                wsh[f * 4 + 0][n] = v.x; wsh[f * 4 + 1][n] = v.y;
                wsh[f * 4 + 2][n] = v.z; wsh[f * 4 + 3][n] = v.w;
            }
        }
        __syncthreads();
        #pragma unroll
        for (int kk = 0; kk < BK; ++kk) {
            float xv[4];
            #pragma unroll
            for (int r = 0; r < 4; ++r) xv[r] = xs[m0 + r][kk];
            float4 w0 = *(const float4*)&wsh[kk][n0];
            float4 w1 = *(const float4*)&wsh[kk][n0 + 4];
            float wv[8] = {w0.x, w0.y, w0.z, w0.w, w1.x, w1.y, w1.z, w1.w};
            #pragma unroll
            for (int r = 0; r < 4; ++r)
                #pragma unroll
                for (int c = 0; c < 8; ++c)
                    acc[r][c] = fmaf(xv[r], wv[c], acc[r][c]);
        }
        __syncthreads();
    }

    float4 b0 = *(const float4*)&b[n0];
    float4 b1 = *(const float4*)&b[n0 + 4];
    #pragma unroll
    for (int r = 0; r < 4; ++r) {
        int gm = m_blk + m0 + r;
        if (gm < N_NODES) {
            float4 o0, o1;
            o0.x = acc[r][0] + b0.x; o0.y = acc[r][1] + b0.y;
            o0.z = acc[r][2] + b0.z; o0.w = acc[r][3] + b0.w;
            o1.x = acc[r][4] + b1.x; o1.y = acc[r][5] + b1.y;
            o1.z = acc[r][6] + b1.z; o1.w = acc[r][7] + b1.w;
            *(float4*)&feat[(size_t)gm * HC + n0]     = o0;
            *(float4*)&feat[(size_t)gm * HC + n0 + 4] = o1;
        }
    }
}

// ---------------------------------------------------------------------------
// Kernel 2: per-node scores. e_src/e_tar = feat @ att cols; e_self = exp(lrelu(...));
// e_sum initialized to e_self. One wave per node.
// ---------------------------------------------------------------------------
__global__ __launch_bounds__(256)
void node_scores(const float* __restrict__ feat, const float* __restrict__ att,
                 float* __restrict__ e_src, float* __restrict__ e_tar,
                 float* __restrict__ e_self, float* __restrict__ e_sum) {
    int node = blockIdx.x * 4 + (threadIdx.x >> 6);
    if (node >= N_NODES) return;
    int lane = threadIdx.x & 63;
    float2 f = *(const float2*)&feat[(size_t)node * HC + lane * 2];
    float4 a = *(const float4*)&att[lane * 4];   // (att[2l][0],att[2l][1],att[2l+1][0],att[2l+1][1])
    float s = f.x * a.x + f.y * a.z;
    float t = f.x * a.y + f.y * a.w;
    #pragma unroll
    for (int off = 32; off; off >>= 1) {
        s += __shfl_xor(s, off);
        t += __shfl_xor(t, off);
    }
    if (lane == 0) {
        e_src[node] = s;
        e_tar[node] = t;
        float z = s + t;
        float lr = z > 0.f ? z : NEG_SLOPE * z;
        float es = expf(lr);
        e_self[node] = es;
        e_sum[node] = es;
    }
}

// ---------------------------------------------------------------------------
// Kernel 3: per-edge score e = exp(lrelu(e_src[src]+e_tar[tar])); atomic into e_sum[tar]
// ---------------------------------------------------------------------------
__global__ __launch_bounds__(256)
void edge_scores(const int* __restrict__ ei, const float* __restrict__ e_src,
                 const float* __restrict__ e_tar, float* __restrict__ e_edge,
                 float* __restrict__ e_sum) {
    int k = blockIdx.x * 256 + threadIdx.x;
    if (k >= N_EDGES) return;
    int t = ei[k];
    int s = ei[N_EDGES + k];
    float z = e_src[s] + e_tar[t];
    float lr = z > 0.f ? z : NEG_SLOPE * z;
    float e = expf(lr);
    e_edge[k] = e;
    atomicAdd(&e_sum[t], e);
}

// ---------------------------------------------------------------------------
// Kernel 4: out = feat * (e_self / e_sum)   (self term; initializes d_out)
// ---------------------------------------------------------------------------
__global__ __launch_bounds__(256)
void self_out(const float* __restrict__ feat, const float* __restrict__ e_self,
              const float* __restrict__ e_sum, float* __restrict__ out) {
    int i = blockIdx.x * 256 + threadIdx.x;      // float4 index
    if (i >= N_NODES * (HC / 4)) return;
    int node = i >> 5;                            // 32 float4 per node
    float sc = e_self[node] / e_sum[node];
    float4 f = ((const float4*)feat)[i];
    float4 o;
    o.x = f.x * sc; o.y = f.y * sc; o.z = f.z * sc; o.w = f.w * sc;
    ((float4*)out)[i] = o;
}

// ---------------------------------------------------------------------------
// Kernel 5: edge aggregation: out[tar] += (e/e_sum[tar]) * feat[src]. One wave/edge.
// ---------------------------------------------------------------------------
__global__ __launch_bounds__(256)
void edge_aggregate(const int* __restrict__ ei, const float* __restrict__ e_edge,
                    const float* __restrict__ e_sum, const float* __restrict__ feat,
                    float* __restrict__ out) {
    int e = blockIdx.x * 4 + (threadIdx.x >> 6);
    if (e >= N_EDGES) return;
    int lane = threadIdx.x & 63;
    int t = ei[e];
    int s = ei[N_EDGES + e];
    float alpha = e_edge[e] / e_sum[t];
    float2 f = *(const float2*)&feat[(size_t)s * HC + lane * 2];
    atomicAdd(&out[(size_t)t * HC + lane * 2],     alpha * f.x);
    atomicAdd(&out[(size_t)t * HC + lane * 2 + 1], alpha * f.y);
}

// ---------------------------------------------------------------------------
extern "C" void kernel_launch(void* const* d_in, const int* in_sizes, int n_in,
                              void* d_out, int out_size, void* d_ws, size_t ws_size,
                              hipStream_t stream) {
    const float* x   = (const float*)d_in[0];
    const int*   ei  = (const int*)d_in[1];     // [0:NE)=tar, [NE:2NE)=src
    const float* W   = (const float*)d_in[2];
    const float* b   = (const float*)d_in[3];
    const float* att = (const float*)d_in[4];
    float* out = (float*)d_out;

    float* feat   = (float*)d_ws;                 // 12.8M floats
    float* e_src  = feat   + (size_t)N_NODES * HC;
    float* e_tar  = e_src  + N_NODES;
    float* e_self = e_tar  + N_NODES;
    float* e_sum  = e_self + N_NODES;
    float* e_edge = e_sum  + N_NODES;             // 1.6M floats

    // 1. feat = x @ W^T + b
    gemm_feat<<<(N_NODES + BM - 1) / BM, 256, 0, stream>>>(x, W, b, feat);
    // 2. per-node scores + e_sum init
    node_scores<<<(N_NODES + 3) / 4, 256, 0, stream>>>(feat, att, e_src, e_tar, e_self, e_sum);
    // 3. per-edge scores + e_sum accumulation
    edge_scores<<<(N_EDGES + 255) / 256, 256, 0, stream>>>(ei, e_src, e_tar, e_edge, e_sum);
    // 4. self term (initializes out)
    self_out<<<(N_NODES * (HC / 4) + 255) / 256, 256, 0, stream>>>(feat, e_self, e_sum, out);
    // 5. edge aggregation with atomics
    edge_aggregate<<<N_EDGES / 4, 256, 0, stream>>>(ei, e_edge, e_sum, feat, out);
}

// Round 2
// 581.525 us; speedup vs baseline: 2.8510x; 2.8510x over previous
//
#include <hip/hip_runtime.h>
#include <hip/hip_bf16.h>
#include <math.h>

#define N_NODES 100000
#define N_EDGES 1600000
#define IN_CH 256
#define HC 128
#define NEG_SLOPE 0.2f
#define SCAN_CHUNK 2048
#define N_CHUNKS ((N_NODES + SCAN_CHUNK - 1) / SCAN_CHUNK)   // 49

// ---------------------------------------------------------------------------
// Kernel 1: feat = x @ W^T + b.  x:(N,256) W:(128,256) feat:(N,128), fp32.
// ---------------------------------------------------------------------------
#define BM 64
#define BN 128
#define BK 32

__global__ __launch_bounds__(256, 2)
void gemm_feat(const float* __restrict__ x, const float* __restrict__ W,
               const float* __restrict__ b, float* __restrict__ feat) {
    __shared__ float xs[BM][BK + 1];
    __shared__ float wsh[BK][BN + 4];

    const int tid  = threadIdx.x;
    const int m_blk = blockIdx.x * BM;
    const int nthr = tid & 15;
    const int mthr = tid >> 4;
    const int n0 = nthr * 8;
    const int m0 = mthr * 4;

    float acc[4][8];
    #pragma unroll
    for (int r = 0; r < 4; ++r)
        #pragma unroll
        for (int c = 0; c < 8; ++c) acc[r][c] = 0.f;

    for (int k0 = 0; k0 < IN_CH; k0 += BK) {
        {
            const int f = tid & 7;
            const int row = tid >> 3;
            #pragma unroll
            for (int i = 0; i < 2; ++i) {
                int r = row + i * 32;
                int gm = m_blk + r;
                float4 v = make_float4(0.f, 0.f, 0.f, 0.f);
                if (gm < N_NODES)
                    v = *(const float4*)&x[(size_t)gm * IN_CH + k0 + f * 4];
                xs[r][f * 4 + 0] = v.x; xs[r][f * 4 + 1] = v.y;
                xs[r][f * 4 + 2] = v.z; xs[r][f * 4 + 3] = v.w;
            }
        }
        {
            const int f = tid & 7;
            const int nb = tid >> 3;
            #pragma unroll
            for (int i = 0; i < 4; ++i) {
                int n = nb + i * 32;
                float4 v = *(const float4*)&W[(size_t)n * IN_CH + k0 + f * 4];
                wsh[f * 4 + 0][n] = v.x; wsh[f * 4 + 1][n] = v.y;
                wsh[f * 4 + 2][n] = v.z; wsh[f * 4 + 3][n] = v.w;
            }
        }
        __syncthreads();
        #pragma unroll
        for (int kk = 0; kk < BK; ++kk) {
            float xv[4];
            #pragma unroll
            for (int r = 0; r < 4; ++r) xv[r] = xs[m0 + r][kk];
            float4 w0 = *(const float4*)&wsh[kk][n0];
            float4 w1 = *(const float4*)&wsh[kk][n0 + 4];
            float wv[8] = {w0.x, w0.y, w0.z, w0.w, w1.x, w1.y, w1.z, w1.w};
            #pragma unroll
            for (int r = 0; r < 4; ++r)
                #pragma unroll
                for (int c = 0; c < 8; ++c)
                    acc[r][c] = fmaf(xv[r], wv[c], acc[r][c]);
        }
        __syncthreads();
    }

    float4 b0 = *(const float4*)&b[n0];
    float4 b1 = *(const float4*)&b[n0 + 4];
    #pragma unroll
    for (int r = 0; r < 4; ++r) {
        int gm = m_blk + m0 + r;
        if (gm < N_NODES) {
            float4 o0, o1;
            o0.x = acc[r][0] + b0.x; o0.y = acc[r][1] + b0.y;
            o0.z = acc[r][2] + b0.z; o0.w = acc[r][3] + b0.w;
            o1.x = acc[r][4] + b1.x; o1.y = acc[r][5] + b1.y;
            o1.z = acc[r][6] + b1.z; o1.w = acc[r][7] + b1.w;
            *(float4*)&feat[(size_t)gm * HC + n0]     = o0;
            *(float4*)&feat[(size_t)gm * HC + n0 + 4] = o1;
        }
    }
}

// ---------------------------------------------------------------------------
// Kernel 2: per-node attention scores (e_src, e_tar, e_self). One wave/node.
// ---------------------------------------------------------------------------
__global__ __launch_bounds__(256)
void node_scores(const float* __restrict__ feat, const float* __restrict__ att,
                 float* __restrict__ e_src, float* __restrict__ e_tar,
                 float* __restrict__ e_self) {
    int node = blockIdx.x * 4 + (threadIdx.x >> 6);
    if (node >= N_NODES) return;
    int lane = threadIdx.x & 63;
    float2 f = *(const float2*)&feat[(size_t)node * HC + lane * 2];
    float4 a = *(const float4*)&att[lane * 4];
    float s = f.x * a.x + f.y * a.z;
    float t = f.x * a.y + f.y * a.w;
    #pragma unroll
    for (int off = 32; off; off >>= 1) {
        s += __shfl_xor(s, off);
        t += __shfl_xor(t, off);
    }
    if (lane == 0) {
        e_src[node] = s;
        e_tar[node] = t;
        float z = s + t;
        float lr = z > 0.f ? z : NEG_SLOPE * z;
        e_self[node] = expf(lr);
    }
}

// ---------------------------------------------------------------------------
// CSR build: histogram -> scan (3 kernels) -> scatter
// ---------------------------------------------------------------------------
__global__ __launch_bounds__(256)
void hist_k(const int* __restrict__ ei, int* __restrict__ deg) {
    int k = blockIdx.x * 256 + threadIdx.x;
    if (k >= N_EDGES) return;
    atomicAdd(&deg[ei[k]], 1);
}

__global__ __launch_bounds__(256)
void scan_chunk_k(const int* __restrict__ deg, int* __restrict__ offsets,
                  int* __restrict__ partial) {
    __shared__ int sdata[256];
    int t = threadIdx.x;
    int base = blockIdx.x * SCAN_CHUNK + t * 8;
    int v[8]; int run = 0;
    #pragma unroll
    for (int i = 0; i < 8; ++i) {
        int idx = base + i;
        int d = (idx < N_NODES) ? deg[idx] : 0;
        run += d;
        v[i] = run;                 // inclusive within thread
    }
    sdata[t] = run;
    __syncthreads();
    for (int off = 1; off < 256; off <<= 1) {
        int x = (t >= off) ? sdata[t - off] : 0;
        __syncthreads();
        sdata[t] += x;
        __syncthreads();
    }
    int excl = sdata[t] - run;      // exclusive prefix of this thread within block
    if (t == 255) partial[blockIdx.x] = sdata[255];
    #pragma unroll
    for (int i = 0; i < 8; ++i) {
        int idx = base + i;
        if (idx < N_NODES) offsets[idx + 1] = excl + v[i];
    }
}

__global__ void scan_partial_k(int* partial) {
    if (threadIdx.x == 0 && blockIdx.x == 0) {
        int run = 0;
        for (int i = 0; i < N_CHUNKS; ++i) {
            int p = partial[i]; partial[i] = run; run += p;
        }
    }
}

__global__ __launch_bounds__(256)
void scan_add_k(int* __restrict__ offsets, const int* __restrict__ partial) {
    int i = blockIdx.x * 256 + threadIdx.x;
    if (i == 0) offsets[0] = 0;
    if (i < N_NODES) offsets[i + 1] += partial[i / SCAN_CHUNK];
}

__global__ __launch_bounds__(256)
void scatter_k(const int* __restrict__ ei, const int* __restrict__ offsets,
               int* __restrict__ cursor, const float* __restrict__ e_src,
               const float* __restrict__ e_tar, int* __restrict__ csr_src,
               float* __restrict__ csr_e) {
    int k = blockIdx.x * 256 + threadIdx.x;
    if (k >= N_EDGES) return;
    int t = ei[k];
    int s = ei[N_EDGES + k];
    int slot = offsets[t] + atomicAdd(&cursor[t], 1);
    float z = e_src[s] + e_tar[t];
    float lr = z > 0.f ? z : NEG_SLOPE * z;
    csr_src[slot] = s;
    csr_e[slot] = expf(lr);
}

// ---------------------------------------------------------------------------
// Aggregate: one wave per node, no atomics.
// out[t] = feat[t]*e_self/(esum+e_self) + sum_j (e_j/(esum+e_self)) * feat[src_j]
// ---------------------------------------------------------------------------
__global__ __launch_bounds__(256)
void aggregate_k(const int* __restrict__ offsets, const int* __restrict__ csr_src,
                 const float* __restrict__ csr_e, const float* __restrict__ feat,
                 const float* __restrict__ e_self, float* __restrict__ out) {
    int node = blockIdx.x * 4 + (threadIdx.x >> 6);
    if (node >= N_NODES) return;
    int lane = threadIdx.x & 63;
    int beg = offsets[node];
    int end = offsets[node + 1];

    float esum = 0.f;
    for (int j = beg + lane; j < end; j += 64) esum += csr_e[j];
    #pragma unroll
    for (int off = 32; off; off >>= 1) esum += __shfl_xor(esum, off);

    float eself = e_self[node];
    float inv = 1.f / (esum + eself);

    float2 f = *(const float2*)&feat[(size_t)node * HC + lane * 2];
    float sc = eself * inv;
    float accx = f.x * sc, accy = f.y * sc;

    int j = beg;
    for (; j + 1 < end; j += 2) {
        float a0 = csr_e[j] * inv;
        float a1 = csr_e[j + 1] * inv;
        int s0 = csr_src[j];
        int s1 = csr_src[j + 1];
        float2 f0 = *(const float2*)&feat[(size_t)s0 * HC + lane * 2];
        float2 f1 = *(const float2*)&feat[(size_t)s1 * HC + lane * 2];
        accx += a0 * f0.x + a1 * f1.x;
        accy += a0 * f0.y + a1 * f1.y;
    }
    if (j < end) {
        float a0 = csr_e[j] * inv;
        int s0 = csr_src[j];
        float2 f0 = *(const float2*)&feat[(size_t)s0 * HC + lane * 2];
        accx += a0 * f0.x;
        accy += a0 * f0.y;
    }
    *(float2*)&out[(size_t)node * HC + lane * 2] = make_float2(accx, accy);
}

// ---------------------------------------------------------------------------
extern "C" void kernel_launch(void* const* d_in, const int* in_sizes, int n_in,
                              void* d_out, int out_size, void* d_ws, size_t ws_size,
                              hipStream_t stream) {
    const float* x   = (const float*)d_in[0];
    const int*   ei  = (const int*)d_in[1];     // [0:NE)=tar, [NE:2NE)=src
    const float* W   = (const float*)d_in[2];
    const float* b   = (const float*)d_in[3];
    const float* att = (const float*)d_in[4];
    float* out = (float*)d_out;

    float* feat    = (float*)d_ws;                         // 12.8M floats
    float* e_src   = feat    + (size_t)N_NODES * HC;
    float* e_tar   = e_src   + N_NODES;
    float* e_self  = e_tar   + N_NODES;
    int*   deg     = (int*)(e_self + N_NODES);             // N_NODES
    int*   offsets = deg     + N_NODES;                    // N_NODES+1
    int*   cursor  = offsets + N_NODES + 1;                // N_NODES
    int*   partial = cursor  + N_NODES;                    // 64
    int*   csr_src = partial + 64;                         // N_EDGES
    float* csr_e   = (float*)(csr_src + N_EDGES);          // N_EDGES

    hipMemsetAsync(deg, 0, N_NODES * sizeof(int), stream);
    hipMemsetAsync(cursor, 0, N_NODES * sizeof(int), stream);

    // CSR topology build (independent of feat)
    hist_k<<<(N_EDGES + 255) / 256, 256, 0, stream>>>(ei, deg);
    scan_chunk_k<<<N_CHUNKS, 256, 0, stream>>>(deg, offsets, partial);
    scan_partial_k<<<1, 64, 0, stream>>>(partial);
    scan_add_k<<<(N_NODES + 255) / 256, 256, 0, stream>>>(offsets, partial);

    // Dense transform + scores
    gemm_feat<<<(N_NODES + BM - 1) / BM, 256, 0, stream>>>(x, W, b, feat);
    node_scores<<<(N_NODES + 3) / 4, 256, 0, stream>>>(feat, att, e_src, e_tar, e_self);

    // Edge scatter into CSR (with edge score computation)
    scatter_k<<<(N_EDGES + 255) / 256, 256, 0, stream>>>(ei, offsets, cursor,
                                                         e_src, e_tar, csr_src, csr_e);

    // Atomic-free aggregation
    aggregate_k<<<(N_NODES + 3) / 4, 256, 0, stream>>>(offsets, csr_src, csr_e,
                                                       feat, e_self, out);
}

// Round 4
// 454.869 us; speedup vs baseline: 3.6449x; 1.2784x over previous
//
#include <hip/hip_runtime.h>
#include <hip/hip_bf16.h>
#include <math.h>

#define N_NODES 100000
#define N_EDGES 1600000
#define IN_CH 256
#define HC 128
#define NEG_SLOPE 0.2f
#define SCAN_CHUNK 2048
#define N_CHUNKS ((N_NODES + SCAN_CHUNK - 1) / SCAN_CHUNK)   // 49

typedef __attribute__((ext_vector_type(8))) short short8;
typedef __attribute__((ext_vector_type(4))) float floatx4;

__device__ inline ushort f2b(float f) {
    __hip_bfloat16 h = __float2bfloat16(f);
    return *(ushort*)&h;
}

// ---------------------------------------------------------------------------
// Kernel 1: feat_bf16 = bf16(x @ W^T + b), plus fused attention scores:
//   e_src/e_tar = feat @ att (fp32 accum), e_self = exp(lrelu(e_src+e_tar)).
// MFMA 16x16x32 bf16. Block = 256 thr (4 waves), BM=128 rows, full N=128.
// Wave w owns rows [w*32, w*32+32) as 2 m-tiles x 8 n-tiles.
// ---------------------------------------------------------------------------
#define GBM 128

__global__ __launch_bounds__(256, 2)
void gemm_mfma(const float* __restrict__ x, const float* __restrict__ W,
               const float* __restrict__ b, const float* __restrict__ att,
               __hip_bfloat16* __restrict__ featb,
               float* __restrict__ e_src, float* __restrict__ e_tar,
               float* __restrict__ e_self) {
    // row stride 72 ushorts = 144 B (16B-aligned, +16B pad -> 2-way-max bank alias)
    __shared__ ushort xs[128][72];
    __shared__ ushort wsh[128][72];

    const int tid  = threadIdx.x;
    const int wave = tid >> 6;
    const int lane = tid & 63;
    const int l16  = lane >> 4;
    const int lc   = lane & 15;
    const int row0 = blockIdx.x * GBM;

    floatx4 acc[2][8];
    #pragma unroll
    for (int mt = 0; mt < 2; ++mt)
        #pragma unroll
        for (int nt = 0; nt < 8; ++nt)
            acc[mt][nt] = (floatx4){0.f, 0.f, 0.f, 0.f};

    for (int kb = 0; kb < 4; ++kb) {           // K chunks of 64
        const int r  = tid >> 4;               // 0..15
        const int kq = tid & 15;               // float4 index within 64
        #pragma unroll
        for (int i = 0; i < 8; ++i) {          // x rows
            int rr = r + i * 16;
            int gr = row0 + rr;
            float4 v = make_float4(0.f, 0.f, 0.f, 0.f);
            if (gr < N_NODES)
                v = *(const float4*)&x[(size_t)gr * IN_CH + kb * 64 + kq * 4];
            ushort4 u;
            u.x = f2b(v.x); u.y = f2b(v.y); u.z = f2b(v.z); u.w = f2b(v.w);
            *(ushort4*)&xs[rr][kq * 4] = u;
        }
        #pragma unroll
        for (int i = 0; i < 8; ++i) {          // W rows (all 128 valid)
            int rr = r + i * 16;
            float4 v = *(const float4*)&W[(size_t)rr * IN_CH + kb * 64 + kq * 4];
            ushort4 u;
            u.x = f2b(v.x); u.y = f2b(v.y); u.z = f2b(v.z); u.w = f2b(v.w);
            *(ushort4*)&wsh[rr][kq * 4] = u;
        }
        __syncthreads();
        #pragma unroll
        for (int ks = 0; ks < 2; ++ks) {       // two K=32 MFMA steps
            short8 a0 = *(short8*)&xs[wave * 32 + lc][ks * 32 + l16 * 8];
            short8 a1 = *(short8*)&xs[wave * 32 + 16 + lc][ks * 32 + l16 * 8];
            short8 bf[8];
            #pragma unroll
            for (int nt = 0; nt < 8; ++nt)
                bf[nt] = *(short8*)&wsh[nt * 16 + lc][ks * 32 + l16 * 8];
            #pragma unroll
            for (int nt = 0; nt < 8; ++nt) {
                acc[0][nt] = __builtin_amdgcn_mfma_f32_16x16x32_bf16(a0, bf[nt], acc[0][nt], 0, 0, 0);
                acc[1][nt] = __builtin_amdgcn_mfma_f32_16x16x32_bf16(a1, bf[nt], acc[1][nt], 0, 0, 0);
            }
        }
        __syncthreads();
    }

    // per-lane att / bias columns: col = nt*16 + lc
    float av0[8], av1[8], bc[8];
    #pragma unroll
    for (int nt = 0; nt < 8; ++nt) {
        float2 av = *(const float2*)&att[(nt * 16 + lc) * 2];
        av0[nt] = av.x; av1[nt] = av.y;
        bc[nt] = b[nt * 16 + lc];
    }

    // C/D layout: lane holds D[m = l16*4 + reg][n = lc] per tile
    #pragma unroll
    for (int mt = 0; mt < 2; ++mt) {
        #pragma unroll
        for (int rg = 0; rg < 4; ++rg) {
            int row = row0 + wave * 32 + mt * 16 + l16 * 4 + rg;
            float s = 0.f, t = 0.f;
            float vals[8];
            #pragma unroll
            for (int nt = 0; nt < 8; ++nt) {
                float v = acc[mt][nt][rg] + bc[nt];
                vals[nt] = v;
                s += v * av0[nt];
                t += v * av1[nt];
            }
            #pragma unroll
            for (int off = 8; off; off >>= 1) {
                s += __shfl_xor(s, off);
                t += __shfl_xor(t, off);
            }
            if (row < N_NODES) {
                if (lc == 0) {
                    e_src[row] = s;
                    e_tar[row] = t;
                    float z = s + t;
                    float lr = z > 0.f ? z : NEG_SLOPE * z;
                    e_self[row] = expf(lr);
                }
                #pragma unroll
                for (int nt = 0; nt < 8; ++nt)
                    featb[(size_t)row * HC + nt * 16 + lc] = __float2bfloat16(vals[nt]);
            }
        }
    }
}

// ---------------------------------------------------------------------------
// CSR build: histogram -> scan (3 kernels) -> scatter (packed int2)
// ---------------------------------------------------------------------------
__global__ __launch_bounds__(256)
void hist_k(const int* __restrict__ ei, int* __restrict__ deg) {
    int k = blockIdx.x * 256 + threadIdx.x;
    if (k >= N_EDGES) return;
    atomicAdd(&deg[ei[k]], 1);
}

__global__ __launch_bounds__(256)
void scan_chunk_k(const int* __restrict__ deg, int* __restrict__ offsets,
                  int* __restrict__ partial) {
    __shared__ int sdata[256];
    int t = threadIdx.x;
    int base = blockIdx.x * SCAN_CHUNK + t * 8;
    int v[8]; int run = 0;
    #pragma unroll
    for (int i = 0; i < 8; ++i) {
        int idx = base + i;
        int d = (idx < N_NODES) ? deg[idx] : 0;
        run += d;
        v[i] = run;
    }
    sdata[t] = run;
    __syncthreads();
    for (int off = 1; off < 256; off <<= 1) {
        int xx = (t >= off) ? sdata[t - off] : 0;
        __syncthreads();
        sdata[t] += xx;
        __syncthreads();
    }
    int excl = sdata[t] - run;
    if (t == 255) partial[blockIdx.x] = sdata[255];
    #pragma unroll
    for (int i = 0; i < 8; ++i) {
        int idx = base + i;
        if (idx < N_NODES) offsets[idx + 1] = excl + v[i];
    }
}

__global__ void scan_partial_k(int* partial) {
    if (threadIdx.x == 0 && blockIdx.x == 0) {
        int run = 0;
        for (int i = 0; i < N_CHUNKS; ++i) {
            int p = partial[i]; partial[i] = run; run += p;
        }
    }
}

__global__ __launch_bounds__(256)
void scan_add_k(int* __restrict__ offsets, const int* __restrict__ partial) {
    int i = blockIdx.x * 256 + threadIdx.x;
    if (i == 0) offsets[0] = 0;
    if (i < N_NODES) offsets[i + 1] += partial[i / SCAN_CHUNK];
}

__global__ __launch_bounds__(256)
void scatter_k(const int* __restrict__ ei, const int* __restrict__ offsets,
               int* __restrict__ cursor, const float* __restrict__ e_src,
               const float* __restrict__ e_tar, int2* __restrict__ csr) {
    int k = blockIdx.x * 256 + threadIdx.x;
    if (k >= N_EDGES) return;
    int t = ei[k];
    int s = ei[N_EDGES + k];
    int slot = offsets[t] + atomicAdd(&cursor[t], 1);
    float z = e_src[s] + e_tar[t];
    float lr = z > 0.f ? z : NEG_SLOPE * z;
    csr[slot] = make_int2(s, __float_as_int(expf(lr)));
}

// ---------------------------------------------------------------------------
// Aggregate: one wave per node, bf16 gathers, no atomics.
// ---------------------------------------------------------------------------
__global__ __launch_bounds__(256)
void aggregate_k(const int* __restrict__ offsets, const int2* __restrict__ csr,
                 const __hip_bfloat162* __restrict__ featb,
                 const float* __restrict__ e_self, float* __restrict__ out) {
    int node = blockIdx.x * 4 + (threadIdx.x >> 6);
    if (node >= N_NODES) return;
    int lane = threadIdx.x & 63;
    int beg = offsets[node];
    int end = offsets[node + 1];

    float esum = 0.f;
    for (int j = beg + lane; j < end; j += 64)
        esum += __int_as_float(csr[j].y);
    #pragma unroll
    for (int off = 32; off; off >>= 1) esum += __shfl_xor(esum, off);

    float eself = e_self[node];
    float inv = 1.f / (esum + eself);

    float2 f = __bfloat1622float2(featb[(size_t)node * 64 + lane]);
    float sc = eself * inv;
    float accx = f.x * sc, accy = f.y * sc;

    int j = beg;
    for (; j + 1 < end; j += 2) {
        int2 c0 = csr[j];
        int2 c1 = csr[j + 1];
        float a0 = __int_as_float(c0.y) * inv;
        float a1 = __int_as_float(c1.y) * inv;
        float2 f0 = __bfloat1622float2(featb[(size_t)c0.x * 64 + lane]);
        float2 f1 = __bfloat1622float2(featb[(size_t)c1.x * 64 + lane]);
        accx += a0 * f0.x + a1 * f1.x;
        accy += a0 * f0.y + a1 * f1.y;
    }
    if (j < end) {
        int2 c0 = csr[j];
        float a0 = __int_as_float(c0.y) * inv;
        float2 f0 = __bfloat1622float2(featb[(size_t)c0.x * 64 + lane]);
        accx += a0 * f0.x;
        accy += a0 * f0.y;
    }
    *(float2*)&out[(size_t)node * HC + lane * 2] = make_float2(accx, accy);
}

// ---------------------------------------------------------------------------
extern "C" void kernel_launch(void* const* d_in, const int* in_sizes, int n_in,
                              void* d_out, int out_size, void* d_ws, size_t ws_size,
                              hipStream_t stream) {
    const float* x   = (const float*)d_in[0];
    const int*   ei  = (const int*)d_in[1];     // [0:NE)=tar, [NE:2NE)=src
    const float* W   = (const float*)d_in[2];
    const float* b   = (const float*)d_in[3];
    const float* att = (const float*)d_in[4];
    float* out = (float*)d_out;

    __hip_bfloat16* featb = (__hip_bfloat16*)d_ws;            // N*128 bf16 = 25.6 MB
    float* e_src   = (float*)(featb + (size_t)N_NODES * HC);
    float* e_tar   = e_src   + N_NODES;
    float* e_self  = e_tar   + N_NODES;
    int*   deg     = (int*)(e_self + N_NODES);
    int*   offsets = deg     + N_NODES;                        // N_NODES+1
    int*   cursor  = offsets + N_NODES + 1;
    int*   partial = cursor  + N_NODES;                        // 64
    int2*  csr     = (int2*)(partial + 64);                    // N_EDGES int2

    (void)hipMemsetAsync(deg, 0, N_NODES * sizeof(int), stream);
    (void)hipMemsetAsync(cursor, 0, N_NODES * sizeof(int), stream);

    // CSR topology (independent of features)
    hist_k<<<(N_EDGES + 255) / 256, 256, 0, stream>>>(ei, deg);
    scan_chunk_k<<<N_CHUNKS, 256, 0, stream>>>(deg, offsets, partial);
    scan_partial_k<<<1, 64, 0, stream>>>(partial);
    scan_add_k<<<(N_NODES + 255) / 256, 256, 0, stream>>>(offsets, partial);

    // Fused MFMA transform + attention scores
    gemm_mfma<<<(N_NODES + GBM - 1) / GBM, 256, 0, stream>>>(x, W, b, att, featb,
                                                             e_src, e_tar, e_self);

    // Edge scatter into packed CSR
    scatter_k<<<(N_EDGES + 255) / 256, 256, 0, stream>>>(ei, offsets, cursor,
                                                         e_src, e_tar, csr);

    // Atomic-free aggregation over bf16 features
    aggregate_k<<<(N_NODES + 3) / 4, 256, 0, stream>>>(offsets, csr,
                                                       (const __hip_bfloat162*)featb,
                                                       e_self, out);
}

// Round 5
// 443.598 us; speedup vs baseline: 3.7375x; 1.0254x over previous
//
#include <hip/hip_runtime.h>
#include <hip/hip_bf16.h>
#include <math.h>

#define N_NODES 100000
#define N_EDGES 1600000
#define IN_CH 256
#define HC 128
#define NEG_SLOPE 0.2f
#define SCAN_CHUNK 2048
#define N_CHUNKS ((N_NODES + SCAN_CHUNK - 1) / SCAN_CHUNK)   // 49

typedef __attribute__((ext_vector_type(8))) short short8;
typedef __attribute__((ext_vector_type(4))) float floatx4;

__device__ inline ushort f2b(float f) {
    __hip_bfloat16 h = __float2bfloat16(f);
    return *(ushort*)&h;
}

// ---------------------------------------------------------------------------
// Kernel 1: feat_bf16 = bf16(x @ W^T + b), fused attention scores.
// MFMA 16x16x32 bf16. Block = 256 thr (4 waves), BM=128 rows, full N=128.
// ---------------------------------------------------------------------------
#define GBM 128

__global__ __launch_bounds__(256, 2)
void gemm_mfma(const float* __restrict__ x, const float* __restrict__ W,
               const float* __restrict__ b, const float* __restrict__ att,
               __hip_bfloat16* __restrict__ featb,
               float* __restrict__ e_src, float* __restrict__ e_tar,
               float* __restrict__ e_self) {
    __shared__ ushort xs[128][72];
    __shared__ ushort wsh[128][72];

    const int tid  = threadIdx.x;
    const int wave = tid >> 6;
    const int lane = tid & 63;
    const int l16  = lane >> 4;
    const int lc   = lane & 15;
    const int row0 = blockIdx.x * GBM;

    floatx4 acc[2][8];
    #pragma unroll
    for (int mt = 0; mt < 2; ++mt)
        #pragma unroll
        for (int nt = 0; nt < 8; ++nt)
            acc[mt][nt] = (floatx4){0.f, 0.f, 0.f, 0.f};

    for (int kb = 0; kb < 4; ++kb) {           // K chunks of 64
        const int r  = tid >> 4;
        const int kq = tid & 15;
        #pragma unroll
        for (int i = 0; i < 8; ++i) {
            int rr = r + i * 16;
            int gr = row0 + rr;
            float4 v = make_float4(0.f, 0.f, 0.f, 0.f);
            if (gr < N_NODES)
                v = *(const float4*)&x[(size_t)gr * IN_CH + kb * 64 + kq * 4];
            ushort4 u;
            u.x = f2b(v.x); u.y = f2b(v.y); u.z = f2b(v.z); u.w = f2b(v.w);
            *(ushort4*)&xs[rr][kq * 4] = u;
        }
        #pragma unroll
        for (int i = 0; i < 8; ++i) {
            int rr = r + i * 16;
            float4 v = *(const float4*)&W[(size_t)rr * IN_CH + kb * 64 + kq * 4];
            ushort4 u;
            u.x = f2b(v.x); u.y = f2b(v.y); u.z = f2b(v.z); u.w = f2b(v.w);
            *(ushort4*)&wsh[rr][kq * 4] = u;
        }
        __syncthreads();
        #pragma unroll
        for (int ks = 0; ks < 2; ++ks) {
            short8 a0 = *(short8*)&xs[wave * 32 + lc][ks * 32 + l16 * 8];
            short8 a1 = *(short8*)&xs[wave * 32 + 16 + lc][ks * 32 + l16 * 8];
            short8 bf[8];
            #pragma unroll
            for (int nt = 0; nt < 8; ++nt)
                bf[nt] = *(short8*)&wsh[nt * 16 + lc][ks * 32 + l16 * 8];
            #pragma unroll
            for (int nt = 0; nt < 8; ++nt) {
                acc[0][nt] = __builtin_amdgcn_mfma_f32_16x16x32_bf16(a0, bf[nt], acc[0][nt], 0, 0, 0);
                acc[1][nt] = __builtin_amdgcn_mfma_f32_16x16x32_bf16(a1, bf[nt], acc[1][nt], 0, 0, 0);
            }
        }
        __syncthreads();
    }

    float av0[8], av1[8], bc[8];
    #pragma unroll
    for (int nt = 0; nt < 8; ++nt) {
        float2 av = *(const float2*)&att[(nt * 16 + lc) * 2];
        av0[nt] = av.x; av1[nt] = av.y;
        bc[nt] = b[nt * 16 + lc];
    }

    #pragma unroll
    for (int mt = 0; mt < 2; ++mt) {
        #pragma unroll
        for (int rg = 0; rg < 4; ++rg) {
            int row = row0 + wave * 32 + mt * 16 + l16 * 4 + rg;
            float s = 0.f, t = 0.f;
            float vals[8];
            #pragma unroll
            for (int nt = 0; nt < 8; ++nt) {
                float v = acc[mt][nt][rg] + bc[nt];
                vals[nt] = v;
                s += v * av0[nt];
                t += v * av1[nt];
            }
            #pragma unroll
            for (int off = 8; off; off >>= 1) {
                s += __shfl_xor(s, off);
                t += __shfl_xor(t, off);
            }
            if (row < N_NODES) {
                if (lc == 0) {
                    e_src[row] = s;
                    e_tar[row] = t;
                    float z = s + t;
                    float lr = z > 0.f ? z : NEG_SLOPE * z;
                    e_self[row] = __expf(lr);
                }
                #pragma unroll
                for (int nt = 0; nt < 8; ++nt)
                    featb[(size_t)row * HC + nt * 16 + lc] = __float2bfloat16(vals[nt]);
            }
        }
    }
}

// ---------------------------------------------------------------------------
// CSR build: histogram -> scan -> scatter (topology only)
// ---------------------------------------------------------------------------
__global__ __launch_bounds__(256)
void hist_k(const int* __restrict__ ei, int* __restrict__ deg) {
    int k = blockIdx.x * 256 + threadIdx.x;
    if (k >= N_EDGES) return;
    atomicAdd(&deg[ei[k]], 1);
}

__global__ __launch_bounds__(256)
void scan_chunk_k(const int* __restrict__ deg, int* __restrict__ offsets,
                  int* __restrict__ partial) {
    __shared__ int sdata[256];
    int t = threadIdx.x;
    int base = blockIdx.x * SCAN_CHUNK + t * 8;
    int v[8]; int run = 0;
    #pragma unroll
    for (int i = 0; i < 8; ++i) {
        int idx = base + i;
        int d = (idx < N_NODES) ? deg[idx] : 0;
        run += d;
        v[i] = run;
    }
    sdata[t] = run;
    __syncthreads();
    for (int off = 1; off < 256; off <<= 1) {
        int xx = (t >= off) ? sdata[t - off] : 0;
        __syncthreads();
        sdata[t] += xx;
        __syncthreads();
    }
    int excl = sdata[t] - run;
    if (t == 255) partial[blockIdx.x] = sdata[255];
    #pragma unroll
    for (int i = 0; i < 8; ++i) {
        int idx = base + i;
        if (idx < N_NODES) offsets[idx + 1] = excl + v[i];
    }
}

__global__ void scan_partial_k(int* partial) {
    if (threadIdx.x == 0 && blockIdx.x == 0) {
        int run = 0;
        for (int i = 0; i < N_CHUNKS; ++i) {
            int p = partial[i]; partial[i] = run; run += p;
        }
    }
}

// finalize offsets AND initialize cursor = offsets (so scatter needs no offsets gather)
__global__ __launch_bounds__(256)
void scan_add_k(int* __restrict__ offsets, int* __restrict__ cursor,
                const int* __restrict__ partial) {
    int i = blockIdx.x * 256 + threadIdx.x;
    if (i == 0) { offsets[0] = 0; cursor[0] = 0; }
    if (i < N_NODES) {
        int v = offsets[i + 1] + partial[i / SCAN_CHUNK];
        offsets[i + 1] = v;
        cursor[i + 1] = v;
    }
}

__global__ __launch_bounds__(256)
void scatter_k(const int* __restrict__ ei, int* __restrict__ cursor,
               int* __restrict__ csr_src) {
    int k = blockIdx.x * 256 + threadIdx.x;
    if (k >= N_EDGES) return;
    int t = ei[k];
    int s = ei[N_EDGES + k];
    int slot = atomicAdd(&cursor[t], 1);
    csr_src[slot] = s;
}

// ---------------------------------------------------------------------------
// Aggregate: one wave per node, SINGLE pass, unnormalized accumulate.
// out[t] = (e_self*feat[t] + sum_j e_j*feat[src_j]) / (e_self + sum_j e_j)
// ---------------------------------------------------------------------------
__device__ inline float edge_e(float z) {
    float lr = z > 0.f ? z : NEG_SLOPE * z;
    return __expf(lr);
}

__global__ __launch_bounds__(256)
void aggregate_k(const int* __restrict__ offsets, const int* __restrict__ csr_src,
                 const float* __restrict__ e_src, const float* __restrict__ e_tar,
                 const __hip_bfloat162* __restrict__ featb,
                 const float* __restrict__ e_self, float* __restrict__ out) {
    int node = blockIdx.x * 4 + (threadIdx.x >> 6);
    if (node >= N_NODES) return;
    int lane = threadIdx.x & 63;
    int beg = offsets[node];
    int end = offsets[node + 1];
    float et = e_tar[node];
    float eself = e_self[node];

    float2 fs = __bfloat1622float2(featb[(size_t)node * 64 + lane]);
    float esum = eself;
    float accx = eself * fs.x, accy = eself * fs.y;

    int j = beg;
    for (; j + 3 < end; j += 4) {
        int s0 = csr_src[j];
        int s1 = csr_src[j + 1];
        int s2 = csr_src[j + 2];
        int s3 = csr_src[j + 3];
        float e0 = edge_e(e_src[s0] + et);
        float e1 = edge_e(e_src[s1] + et);
        float e2 = edge_e(e_src[s2] + et);
        float e3 = edge_e(e_src[s3] + et);
        float2 f0 = __bfloat1622float2(featb[(size_t)s0 * 64 + lane]);
        float2 f1 = __bfloat1622float2(featb[(size_t)s1 * 64 + lane]);
        float2 f2 = __bfloat1622float2(featb[(size_t)s2 * 64 + lane]);
        float2 f3 = __bfloat1622float2(featb[(size_t)s3 * 64 + lane]);
        esum += (e0 + e1) + (e2 + e3);
        accx += e0 * f0.x + e1 * f1.x + e2 * f2.x + e3 * f3.x;
        accy += e0 * f0.y + e1 * f1.y + e2 * f2.y + e3 * f3.y;
    }
    for (; j < end; ++j) {
        int s0 = csr_src[j];
        float e0 = edge_e(e_src[s0] + et);
        float2 f0 = __bfloat1622float2(featb[(size_t)s0 * 64 + lane]);
        esum += e0;
        accx += e0 * f0.x;
        accy += e0 * f0.y;
    }
    float inv = 1.f / esum;
    *(float2*)&out[(size_t)node * HC + lane * 2] = make_float2(accx * inv, accy * inv);
}

// ---------------------------------------------------------------------------
extern "C" void kernel_launch(void* const* d_in, const int* in_sizes, int n_in,
                              void* d_out, int out_size, void* d_ws, size_t ws_size,
                              hipStream_t stream) {
    const float* x   = (const float*)d_in[0];
    const int*   ei  = (const int*)d_in[1];     // [0:NE)=tar, [NE:2NE)=src
    const float* W   = (const float*)d_in[2];
    const float* b   = (const float*)d_in[3];
    const float* att = (const float*)d_in[4];
    float* out = (float*)d_out;

    __hip_bfloat16* featb = (__hip_bfloat16*)d_ws;            // N*128 bf16 = 25.6 MB
    float* e_src   = (float*)(featb + (size_t)N_NODES * HC);
    float* e_tar   = e_src   + N_NODES;
    float* e_self  = e_tar   + N_NODES;
    int*   deg     = (int*)(e_self + N_NODES);                 // N
    int*   offsets = deg     + N_NODES;                        // N+1
    int*   cursor  = offsets + N_NODES + 1;                    // N+1
    int*   partial = cursor  + N_NODES + 1;                    // 64
    int*   csr_src = partial + 64;                             // N_EDGES

    (void)hipMemsetAsync(deg, 0, N_NODES * sizeof(int), stream);

    // CSR topology (independent of features)
    hist_k<<<(N_EDGES + 255) / 256, 256, 0, stream>>>(ei, deg);
    scan_chunk_k<<<N_CHUNKS, 256, 0, stream>>>(deg, offsets, partial);
    scan_partial_k<<<1, 64, 0, stream>>>(partial);
    scan_add_k<<<(N_NODES + 255) / 256, 256, 0, stream>>>(offsets, cursor, partial);
    scatter_k<<<(N_EDGES + 255) / 256, 256, 0, stream>>>(ei, cursor, csr_src);

    // Fused MFMA transform + attention scores
    gemm_mfma<<<(N_NODES + GBM - 1) / GBM, 256, 0, stream>>>(x, W, b, att, featb,
                                                             e_src, e_tar, e_self);

    // Single-pass atomic-free aggregation
    aggregate_k<<<(N_NODES + 3) / 4, 256, 0, stream>>>(offsets, csr_src, e_src, e_tar,
                                                       (const __hip_bfloat162*)featb,
                                                       e_self, out);
}